// Round 2
// baseline (1856.806 us; speedup 1.0000x reference)
//
#include <hip/hip_runtime.h>
#include <math.h>

// ---------------- wave helpers (wave64) ----------------
__device__ inline float wave_sum(float v){
  #pragma unroll
  for (int off = 1; off < 64; off <<= 1) v += __shfl_xor(v, off, 64);
  return v;
}
__device__ inline float wave_max(float v){
  #pragma unroll
  for (int off = 1; off < 64; off <<= 1) v = fmaxf(v, __shfl_xor(v, off, 64));
  return v;
}

// ---------------- CSR build ----------------
__global__ void k_zero_int(int* __restrict__ p, int n){
  int i = blockIdx.x * 256 + threadIdx.x;
  if (i < n) p[i] = 0;
}

__global__ void k_count(const int* __restrict__ ei, int E, int Etot, int* __restrict__ counts){
  int e = blockIdx.x * 256 + threadIdx.x;
  if (e >= Etot) return;
  int d = (e < E) ? ei[E + e] : (e - E);
  atomicAdd(&counts[d], 1);
}

// single-block exclusive scan over N counts; writes row_ptr[0..N] and resets cursor
__global__ void k_scan(int* __restrict__ counts_cursor, int* __restrict__ row_ptr, int N){
  __shared__ int sd[1024];
  __shared__ int carry;
  int tid = threadIdx.x;
  if (tid == 0) carry = 0;
  __syncthreads();
  int nch = (N + 1023) / 1024;
  for (int ch = 0; ch < nch; ++ch){
    int i = ch * 1024 + tid;
    int v = (i < N) ? counts_cursor[i] : 0;
    sd[tid] = v;
    __syncthreads();
    for (int off = 1; off < 1024; off <<= 1){
      int t = (tid >= off) ? sd[tid - off] : 0;
      __syncthreads();
      sd[tid] += t;
      __syncthreads();
    }
    int excl = sd[tid] - v;
    int base = carry;
    if (i < N){ row_ptr[i] = base + excl; counts_cursor[i] = base + excl; }
    int total = sd[1023];
    __syncthreads();
    if (tid == 0) carry = base + total;
    __syncthreads();
  }
  if (tid == 0) row_ptr[N] = carry;
}

// fill CSR: srcs[pos] = src node; epos[e] = CSR slot of original edge e
__global__ void k_fill(const int* __restrict__ ei, int E, int Etot,
                       int* __restrict__ cursor, int* __restrict__ srcs,
                       int* __restrict__ epos){
  int e = blockIdx.x * 256 + threadIdx.x;
  if (e >= Etot) return;
  int s, d;
  if (e < E){ s = ei[e]; d = ei[E + e]; } else { s = e - E; d = e - E; }
  int pos = atomicAdd(&cursor[d], 1);
  srcs[pos] = s;
  epos[e] = pos;
}

// ---------------- layer 0 projection (K=1) ----------------
__global__ void k_l0_proj(const float* __restrict__ x,
                          const float* __restrict__ Wl, const float* __restrict__ bl,
                          const float* __restrict__ Wr, const float* __restrict__ br,
                          float* __restrict__ xl, float* __restrict__ xr, int N){
  int i = blockIdx.x * 256 + threadIdx.x;
  if (i >= N * 256) return;
  int v = i >> 8, j = i & 255;
  float xv = x[v];
  xl[i] = fmaf(xv, Wl[j], bl[j]);
  xr[i] = fmaf(xv, Wr[j], br[j]);
}

// ---------------- generic fused xl/xr projection GEMM ----------------
// block = C threads, BM nodes per block, full-K A tile in LDS
template<int K, int C, int BM>
__global__ __launch_bounds__(C) void k_gemm_xlxr(const float* __restrict__ h,
    const float* __restrict__ Wl, const float* __restrict__ bl,
    const float* __restrict__ Wr, const float* __restrict__ br,
    float* __restrict__ xl, float* __restrict__ xr, int N){
  __shared__ float As[BM][K];
  int tid = threadIdx.x;
  int v0 = blockIdx.x * BM;
  for (int i = tid; i < BM * K; i += C){
    int r = i / K, c = i % K;
    int vr = v0 + r;
    As[r][c] = (vr < N) ? h[(size_t)vr * K + c] : 0.f;
  }
  __syncthreads();
  float accL[BM], accR[BM];
  float blv = bl[tid], brv = br[tid];
  #pragma unroll
  for (int m = 0; m < BM; ++m){ accL[m] = blv; accR[m] = brv; }
  for (int k = 0; k < K; k += 4){
    float wl[4], wr[4];
    #pragma unroll
    for (int i = 0; i < 4; ++i){
      wl[i] = Wl[(size_t)(k + i) * C + tid];
      wr[i] = Wr[(size_t)(k + i) * C + tid];
    }
    #pragma unroll
    for (int m = 0; m < BM; ++m){
      float4 a = *reinterpret_cast<const float4*>(&As[m][k]);
      accL[m] = fmaf(a.x, wl[0], accL[m]);
      accL[m] = fmaf(a.y, wl[1], accL[m]);
      accL[m] = fmaf(a.z, wl[2], accL[m]);
      accL[m] = fmaf(a.w, wl[3], accL[m]);
      accR[m] = fmaf(a.x, wr[0], accR[m]);
      accR[m] = fmaf(a.y, wr[1], accR[m]);
      accR[m] = fmaf(a.z, wr[2], accR[m]);
      accR[m] = fmaf(a.w, wr[3], accR[m]);
    }
  }
  #pragma unroll
  for (int m = 0; m < BM; ++m){
    int vr = v0 + m;
    if (vr < N){
      xl[(size_t)vr * C + tid] = accL[m];
      xr[(size_t)vr * C + tid] = accR[m];
    }
  }
}

// ---------------- per-edge attention logits (written to CSR slot) ----------------
// one wave per edge; H heads of 64 channels
template<int C, int H>
__global__ void k_edge_logits(const float* __restrict__ xl, const float* __restrict__ xr,
                              const float* __restrict__ att, const int* __restrict__ ei,
                              const int* __restrict__ epos,
                              int E, int Etot, float* __restrict__ logits){
  int idx = blockIdx.x * 256 + threadIdx.x;
  int gw = idx >> 6;
  int lane = threadIdx.x & 63;
  if (gw >= Etot) return;
  int s, d;
  if (gw < E){ s = ei[gw]; d = ei[E + gw]; } else { s = gw - E; d = gw - E; }
  const float* xls = xl + (size_t)s * C;
  const float* xrd = xr + (size_t)d * C;
  size_t pos = (size_t)epos[gw];
  #pragma unroll
  for (int h = 0; h < H; ++h){
    float a = xls[h * 64 + lane] + xrd[h * 64 + lane];
    a = (a > 0.f) ? a : 0.2f * a;
    float p = att[h * 64 + lane] * a;
    p = wave_sum(p);
    if (lane == 0) logits[pos * H + h] = p;
  }
}

// ---------------- per-node softmax + aggregate + bias + LN + ELU ----------------
template<int C, int H>
__global__ __launch_bounds__(C) void k_node_agg(const float* __restrict__ xl,
    const float* __restrict__ logits,
    const int* __restrict__ row_ptr, const int* __restrict__ srcs,
    const float* __restrict__ bias, const float* __restrict__ g, const float* __restrict__ be,
    float* __restrict__ hout, int N){
  constexpr int NW = C / 64;
  int v = blockIdx.x;
  if (v >= N) return;
  int tid = threadIdx.x;
  int h = tid >> 6;
  int lane = tid & 63;
  int r0 = row_ptr[v], r1 = row_ptr[v + 1];
  // segment max (per head)
  float mx = -1e30f;
  for (int e = r0 + lane; e < r1; e += 64) mx = fmaxf(mx, logits[(size_t)e * H + h]);
  mx = wave_max(mx);
  // segment sum of exp
  float sm = 0.f;
  for (int e = r0 + lane; e < r1; e += 64) sm += expf(logits[(size_t)e * H + h] - mx);
  sm = wave_sum(sm);
  float inv = 1.f / (sm + 1e-16f);
  // weighted aggregate of xl[src]
  float acc = 0.f;
  for (int e = r0; e < r1; ++e){
    float w = expf(logits[(size_t)e * H + h] - mx) * inv;
    acc = fmaf(w, xl[(size_t)srcs[e] * C + tid], acc);
  }
  acc += bias[tid];
  // LayerNorm over C channels
  __shared__ float red[NW];
  float s1 = wave_sum(acc);
  if (lane == 0) red[h] = s1;
  __syncthreads();
  float tot = 0.f;
  #pragma unroll
  for (int w = 0; w < NW; ++w) tot += red[w];
  float mu = tot / (float)C;
  float dv = acc - mu;
  __syncthreads();
  float s2 = wave_sum(dv * dv);
  if (lane == 0) red[h] = s2;
  __syncthreads();
  float tot2 = 0.f;
  #pragma unroll
  for (int w = 0; w < NW; ++w) tot2 += red[w];
  float var = tot2 / (float)C;
  float y = dv * rsqrtf(var + 1e-5f) * g[tid] + be[tid];
  hout[(size_t)v * C + tid] = (y > 0.f) ? y : expm1f(y);
}

// ---------------- head MLP on node 0 ----------------
__global__ void k_head(const float* __restrict__ h2,
                       const float* __restrict__ rw1, const float* __restrict__ rb1,
                       const float* __restrict__ rw2, const float* __restrict__ rb2,
                       float* __restrict__ out){
  __shared__ float hv[64];
  int tid = threadIdx.x; // 64 threads
  hv[tid] = h2[tid];
  __syncthreads();
  float contrib = 0.f;
  if (tid < 32){
    float a = rb1[tid];
    #pragma unroll 8
    for (int c = 0; c < 64; ++c) a = fmaf(hv[c], rw1[c * 32 + tid], a);
    float z = 0.5f * a * (1.f + erff(a * 0.70710678118654752f)); // exact GELU
    contrib = z * rw2[tid];
  }
  float s = wave_sum(contrib);
  if (tid == 0) out[0] = s + rb2[0];
}

// ---------------- launch ----------------
extern "C" void kernel_launch(void* const* d_in, const int* in_sizes, int n_in,
                              void* d_out, int out_size, void* d_ws, size_t ws_size,
                              hipStream_t stream){
  const float* x    = (const float*)d_in[0];
  const int*   ei   = (const int*)  d_in[1];
  const float* Wl0  = (const float*)d_in[2];
  const float* bl0  = (const float*)d_in[3];
  const float* Wr0  = (const float*)d_in[4];
  const float* br0  = (const float*)d_in[5];
  const float* att0 = (const float*)d_in[6];
  const float* bias0= (const float*)d_in[7];
  const float* Wl1  = (const float*)d_in[8];
  const float* bl1  = (const float*)d_in[9];
  const float* Wr1  = (const float*)d_in[10];
  const float* br1  = (const float*)d_in[11];
  const float* att1 = (const float*)d_in[12];
  const float* bias1= (const float*)d_in[13];
  const float* Wl2  = (const float*)d_in[14];
  const float* bl2  = (const float*)d_in[15];
  const float* Wr2  = (const float*)d_in[16];
  const float* br2  = (const float*)d_in[17];
  const float* att2 = (const float*)d_in[18];
  const float* bias2= (const float*)d_in[19];
  const float* g0   = (const float*)d_in[20];
  const float* be0  = (const float*)d_in[21];
  const float* g1   = (const float*)d_in[22];
  const float* be1  = (const float*)d_in[23];
  const float* g2   = (const float*)d_in[24];
  const float* be2  = (const float*)d_in[25];
  const float* rw1  = (const float*)d_in[26];
  const float* rb1  = (const float*)d_in[27];
  const float* rw2  = (const float*)d_in[28];
  const float* rb2  = (const float*)d_in[29];

  const int N = in_sizes[0];        // 50000
  const int E = in_sizes[1] / 2;    // 800000
  const int Etot = N + E;           // 850000

  char* ws = (char*)d_ws;
  size_t off = 0;
  auto alloc = [&](size_t bytes) -> char* {
    char* p = ws + off;
    off += (bytes + 255) & ~(size_t)255;
    return p;
  };
  int*   cursor  = (int*)  alloc((size_t)N * 4);
  int*   row_ptr = (int*)  alloc((size_t)(N + 1) * 4);
  int*   srcs    = (int*)  alloc((size_t)Etot * 4);
  int*   epos    = (int*)  alloc((size_t)Etot * 4);
  float* xl      = (float*)alloc((size_t)N * 256 * 4);
  float* xr      = (float*)alloc((size_t)N * 256 * 4);
  float* logits  = (float*)alloc((size_t)Etot * 4 * 4);
  float* hbuf    = (float*)alloc((size_t)N * 256 * 4);
  (void)ws_size; (void)n_in; (void)out_size;

  int eb  = (Etot + 255) / 256;  // edge-parallel blocks
  int elb = (Etot + 3) / 4;      // wave-per-edge blocks (4 waves/block)

  // CSR build (by dst)
  k_zero_int<<<(N + 255) / 256, 256, 0, stream>>>(cursor, N);
  k_count<<<eb, 256, 0, stream>>>(ei, E, Etot, cursor);
  k_scan<<<1, 1024, 0, stream>>>(cursor, row_ptr, N);
  k_fill<<<eb, 256, 0, stream>>>(ei, E, Etot, cursor, srcs, epos);

  // ---- layer 0 (in=1 -> 4 heads x 64, concat) ----
  k_l0_proj<<<(N * 256 + 255) / 256, 256, 0, stream>>>(x, Wl0, bl0, Wr0, br0, xl, xr, N);
  k_edge_logits<256, 4><<<elb, 256, 0, stream>>>(xl, xr, att0, ei, epos, E, Etot, logits);
  k_node_agg<256, 4><<<N, 256, 0, stream>>>(xl, logits, row_ptr, srcs, bias0, g0, be0, hbuf, N);

  // ---- layer 1 (256 -> 4 heads x 64, concat) ----
  k_gemm_xlxr<256, 256, 16><<<(N + 15) / 16, 256, 0, stream>>>(hbuf, Wl1, bl1, Wr1, br1, xl, xr, N);
  k_edge_logits<256, 4><<<elb, 256, 0, stream>>>(xl, xr, att1, ei, epos, E, Etot, logits);
  k_node_agg<256, 4><<<N, 256, 0, stream>>>(xl, logits, row_ptr, srcs, bias1, g1, be1, hbuf, N);

  // ---- layer 2 (256 -> 1 head x 64, mean over 1 head) ----
  k_gemm_xlxr<256, 64, 16><<<(N + 15) / 16, 64, 0, stream>>>(hbuf, Wl2, bl2, Wr2, br2, xl, xr, N);
  k_edge_logits<64, 1><<<elb, 256, 0, stream>>>(xl, xr, att2, ei, epos, E, Etot, logits);
  k_node_agg<64, 1><<<N, 64, 0, stream>>>(xl, logits, row_ptr, srcs, bias2, g2, be2, hbuf, N);

  // ---- head MLP on node 0 ----
  k_head<<<1, 64, 0, stream>>>(hbuf, rw1, rb1, rw2, rb2, (float*)d_out);
}

// Round 3
// 117.256 us; speedup vs baseline: 15.8354x; 15.8354x over previous
//
#include <hip/hip_runtime.h>
#include <math.h>

#define CTR_CNT2 0   // |A2|
#define CTR_CNT1 1   // |A1|
#define CTR_E2   2   // #edges into node 0

// ---------------- wave helpers (wave64) ----------------
__device__ inline float wave_sum(float v){
  #pragma unroll
  for (int off = 1; off < 64; off <<= 1) v += __shfl_xor(v, off, 64);
  return v;
}

// ---------------- init: zero flags/counts, seed node 0 ----------------
__global__ void k_init(int* __restrict__ flag1, int* __restrict__ flag2,
                       int* __restrict__ counts0, int* __restrict__ counts1,
                       int* __restrict__ list2, int* __restrict__ ctr, int N){
  int i = blockIdx.x * 256 + threadIdx.x;
  if (i < N){
    flag1[i] = 0;
    counts0[i] = 0;
    counts1[i] = 0;
    flag2[i] = (i == 0) ? 1 : 0;   // node 0 = A2 index 0
  }
  if (i == 0){
    list2[0] = 0;
    ctr[CTR_CNT2] = 1;
    ctr[CTR_CNT1] = 0;
    ctr[CTR_E2] = 0;
  }
}

// ---------------- pass A: edges into node 0 -> E2 list, A2 set ----------------
__global__ void k_passA(const int* __restrict__ ei, int E,
                        int* __restrict__ flag2, int* __restrict__ list2,
                        int* __restrict__ E2src, int* __restrict__ ctr){
  int e = blockIdx.x * 256 + threadIdx.x;
  if (e >= E) return;
  int d = ei[E + e];
  if (d != 0) return;
  int s = ei[e];
  int p = atomicAdd(&ctr[CTR_E2], 1);
  E2src[p] = s;
  if (atomicCAS(&flag2[s], 0, -1) == 0){
    int idx = atomicAdd(&ctr[CTR_CNT2], 1);
    list2[idx] = s;
    flag2[s] = idx + 1;
  }
}

// ---------------- seed A1 with A2 ----------------
__global__ void k_seed1(const int* __restrict__ list2, int* __restrict__ list1,
                        int* __restrict__ flag1, int* __restrict__ ctr){
  int cnt2 = ctr[CTR_CNT2];
  for (int i = threadIdx.x; i < cnt2; i += 256){
    int v = list2[i];
    list1[i] = v;
    flag1[v] = i + 1;
  }
  __syncthreads();
  if (threadIdx.x == 0) ctr[CTR_CNT1] = cnt2;
}

// ---------------- pass B1: count edges into A2 (by a2 idx), discover A1 ----------------
__global__ void k_passB1(const int* __restrict__ ei, int E,
                         const int* __restrict__ flag2,
                         int* __restrict__ counts1,
                         int* __restrict__ flag1, int* __restrict__ list1,
                         int* __restrict__ ctr){
  int e = blockIdx.x * 256 + threadIdx.x;
  if (e >= E) return;
  int f = flag2[ei[E + e]];
  if (f <= 0) return;
  int s = ei[e];
  atomicAdd(&counts1[f - 1], 1);
  if (atomicCAS(&flag1[s], 0, -1) == 0){
    int idx = atomicAdd(&ctr[CTR_CNT1], 1);
    list1[idx] = s;
    flag1[s] = idx + 1;
  }
}

// ---------------- chunked exclusive scan (single block, 1024 thr) ----------------
// counts_cursor: in counts, out row starts (cursor); rowptr: row starts + total at [cnt]
__global__ void k_scan(int* __restrict__ counts_cursor, int* __restrict__ rowptr,
                       const int* __restrict__ ctr, int ctr_idx){
  __shared__ int sd[1024];
  __shared__ int carry;
  int cnt = ctr[ctr_idx];
  int tid = threadIdx.x;
  if (tid == 0) carry = 0;
  __syncthreads();
  int nch = (cnt + 1023) / 1024;
  for (int ch = 0; ch < nch; ++ch){
    int i = ch * 1024 + tid;
    int v = (i < cnt) ? counts_cursor[i] : 0;
    sd[tid] = v;
    __syncthreads();
    for (int off = 1; off < 1024; off <<= 1){
      int t = (tid >= off) ? sd[tid - off] : 0;
      __syncthreads();
      sd[tid] += t;
      __syncthreads();
    }
    int excl = sd[tid] - v;
    int base = carry;
    if (i < cnt){ rowptr[i] = base + excl; counts_cursor[i] = base + excl; }
    int total = sd[1023];
    __syncthreads();
    if (tid == 0) carry = base + total;
    __syncthreads();
  }
  if (tid == 0) rowptr[cnt] = carry;
}

// ---------------- pass B2: fill srcs of edges into A2 ----------------
__global__ void k_passB2(const int* __restrict__ ei, int E,
                         const int* __restrict__ flag2,
                         int* __restrict__ cursor1, int* __restrict__ srcs1){
  int e = blockIdx.x * 256 + threadIdx.x;
  if (e >= E) return;
  int f = flag2[ei[E + e]];
  if (f <= 0) return;
  int pos = atomicAdd(&cursor1[f - 1], 1);
  srcs1[pos] = ei[e];
}

// ---------------- pass C1/C2: same for edges into A1 ----------------
__global__ void k_passC1(const int* __restrict__ ei, int E,
                         const int* __restrict__ flag1, int* __restrict__ counts0){
  int e = blockIdx.x * 256 + threadIdx.x;
  if (e >= E) return;
  int f = flag1[ei[E + e]];
  if (f <= 0) return;
  atomicAdd(&counts0[f - 1], 1);
}

__global__ void k_passC2(const int* __restrict__ ei, int E,
                         const int* __restrict__ flag1,
                         int* __restrict__ cursor0, int* __restrict__ srcs0){
  int e = blockIdx.x * 256 + threadIdx.x;
  if (e >= E) return;
  int f = flag1[ei[E + e]];
  if (f <= 0) return;
  int pos = atomicAdd(&cursor0[f - 1], 1);
  srcs0[pos] = ei[e];
}

// ---------------- layer 0: flash softmax-agg + bias + LN + ELU for A1 nodes ----------------
__global__ __launch_bounds__(256) void k_l0agg(const float* __restrict__ x,
    const float* __restrict__ Wl0, const float* __restrict__ bl0,
    const float* __restrict__ Wr0, const float* __restrict__ br0,
    const float* __restrict__ att0, const float* __restrict__ bias0,
    const float* __restrict__ g0, const float* __restrict__ be0,
    const int* __restrict__ list1, const int* __restrict__ rowptr0,
    const int* __restrict__ srcs0, const int* __restrict__ ctr,
    float* __restrict__ h0){
  int tid = threadIdx.x;
  int h = tid >> 6, lane = tid & 63;
  float wl = Wl0[tid], blv = bl0[tid], wr = Wr0[tid], brv = br0[tid];
  float at = att0[tid];
  __shared__ float red[4];
  int cnt1 = ctr[CTR_CNT1];
  for (int i = blockIdx.x; i < cnt1; i += gridDim.x){
    int v = list1[i];
    float xr = fmaf(x[v], wr, brv);
    int r0 = rowptr0[i], r1 = rowptr0[i + 1];
    float m = -INFINITY, ssum = 0.f, acc = 0.f;
    for (int e = r0; e <= r1; ++e){           // slot r1 = synthetic self-loop
      int s = (e < r1) ? srcs0[e] : v;
      float xls = fmaf(x[s], wl, blv);
      float a = xls + xr;
      a = (a > 0.f) ? a : 0.2f * a;
      float lg = wave_sum(at * a);
      float mn = fmaxf(m, lg);
      float sc = expf(m - mn), p = expf(lg - mn);
      ssum = fmaf(ssum, sc, p);
      acc  = fmaf(acc,  sc, p * xls);
      m = mn;
    }
    float o = acc / (ssum + 1e-16f) + bias0[tid];
    float s1 = wave_sum(o);
    if (lane == 0) red[h] = s1;
    __syncthreads();
    float mu = (red[0] + red[1] + red[2] + red[3]) * (1.f / 256.f);
    float dv = o - mu;
    __syncthreads();
    float s2 = wave_sum(dv * dv);
    if (lane == 0) red[h] = s2;
    __syncthreads();
    float var = (red[0] + red[1] + red[2] + red[3]) * (1.f / 256.f);
    float y = dv * rsqrtf(var + 1e-5f) * g0[tid] + be0[tid];
    h0[(size_t)v * 256 + tid] = (y > 0.f) ? y : expm1f(y);
    __syncthreads();
  }
}

// ---------------- layer 1 projection (xl only) for A1 nodes ----------------
__global__ __launch_bounds__(256) void k_l1proj(const float* __restrict__ h0,
    const float* __restrict__ Wl1, const float* __restrict__ bl1,
    const int* __restrict__ list1, const int* __restrict__ ctr,
    float* __restrict__ xl1){
  __shared__ float hs[256];
  int tid = threadIdx.x;
  int cnt1 = ctr[CTR_CNT1];
  for (int i = blockIdx.x; i < cnt1; i += gridDim.x){
    int v = list1[i];
    hs[tid] = h0[(size_t)v * 256 + tid];
    __syncthreads();
    float acc = bl1[tid];
    #pragma unroll 8
    for (int k = 0; k < 256; ++k) acc = fmaf(hs[k], Wl1[(size_t)k * 256 + tid], acc);
    xl1[(size_t)v * 256 + tid] = acc;
    __syncthreads();
  }
}

// ---------------- layer 1: xr on the fly + flash agg + LN + ELU for A2 nodes ----------------
__global__ __launch_bounds__(256) void k_l1agg(const float* __restrict__ h0,
    const float* __restrict__ xl1,
    const float* __restrict__ Wr1, const float* __restrict__ br1,
    const float* __restrict__ att1, const float* __restrict__ bias1,
    const float* __restrict__ g1, const float* __restrict__ be1,
    const int* __restrict__ list2, const int* __restrict__ rowptr1,
    const int* __restrict__ srcs1, const int* __restrict__ ctr,
    float* __restrict__ h1){
  __shared__ float hs[256];
  __shared__ float red[4];
  int tid = threadIdx.x;
  int h = tid >> 6, lane = tid & 63;
  float at = att1[tid];
  int cnt2 = ctr[CTR_CNT2];
  for (int i = blockIdx.x; i < cnt2; i += gridDim.x){
    int v = list2[i];
    hs[tid] = h0[(size_t)v * 256 + tid];
    __syncthreads();
    float xr = br1[tid];
    #pragma unroll 8
    for (int k = 0; k < 256; ++k) xr = fmaf(hs[k], Wr1[(size_t)k * 256 + tid], xr);
    int r0 = rowptr1[i], r1 = rowptr1[i + 1];
    float m = -INFINITY, ssum = 0.f, acc = 0.f;
    for (int e = r0; e <= r1; ++e){
      int s = (e < r1) ? srcs1[e] : v;
      float xls = xl1[(size_t)s * 256 + tid];
      float a = xls + xr;
      a = (a > 0.f) ? a : 0.2f * a;
      float lg = wave_sum(at * a);
      float mn = fmaxf(m, lg);
      float sc = expf(m - mn), p = expf(lg - mn);
      ssum = fmaf(ssum, sc, p);
      acc  = fmaf(acc,  sc, p * xls);
      m = mn;
    }
    float o = acc / (ssum + 1e-16f) + bias1[tid];
    float s1 = wave_sum(o);
    if (lane == 0) red[h] = s1;
    __syncthreads();
    float mu = (red[0] + red[1] + red[2] + red[3]) * (1.f / 256.f);
    float dv = o - mu;
    __syncthreads();
    float s2 = wave_sum(dv * dv);
    if (lane == 0) red[h] = s2;
    __syncthreads();
    float var = (red[0] + red[1] + red[2] + red[3]) * (1.f / 256.f);
    float y = dv * rsqrtf(var + 1e-5f) * g1[tid] + be1[tid];
    h1[(size_t)v * 256 + tid] = (y > 0.f) ? y : expm1f(y);
    __syncthreads();
  }
}

// ---------------- layer 2 projection (xl2 for A2 nodes; xr2 for node 0) ----------------
__global__ __launch_bounds__(64) void k_l2proj(const float* __restrict__ h1,
    const float* __restrict__ Wl2, const float* __restrict__ bl2,
    const float* __restrict__ Wr2, const float* __restrict__ br2,
    const int* __restrict__ list2, const int* __restrict__ ctr,
    float* __restrict__ xl2, float* __restrict__ xr2){
  __shared__ float hs[256];
  int tid = threadIdx.x;
  int cnt2 = ctr[CTR_CNT2];
  for (int i = blockIdx.x; i < cnt2; i += gridDim.x){
    int v = list2[i];
    for (int k = tid; k < 256; k += 64) hs[k] = h1[(size_t)v * 256 + k];
    __syncthreads();
    float a = bl2[tid];
    #pragma unroll 8
    for (int k = 0; k < 256; ++k) a = fmaf(hs[k], Wl2[(size_t)k * 64 + tid], a);
    xl2[(size_t)i * 64 + tid] = a;
    if (i == 0){  // node 0 is A2 index 0
      float b = br2[tid];
      #pragma unroll 8
      for (int k = 0; k < 256; ++k) b = fmaf(hs[k], Wr2[(size_t)k * 64 + tid], b);
      xr2[tid] = b;
    }
    __syncthreads();
  }
}

// ---------------- final: layer-2 flash agg for node 0 + LN + ELU + head MLP ----------------
__global__ __launch_bounds__(64) void k_final(const float* __restrict__ xl2,
    const float* __restrict__ xr2,
    const float* __restrict__ att2, const float* __restrict__ bias2,
    const float* __restrict__ g2, const float* __restrict__ be2,
    const float* __restrict__ rw1, const float* __restrict__ rb1,
    const float* __restrict__ rw2, const float* __restrict__ rb2,
    const int* __restrict__ E2src, const int* __restrict__ flag2,
    const int* __restrict__ ctr, float* __restrict__ out){
  int lane = threadIdx.x;
  float xr = xr2[lane], at = att2[lane];
  int ne = ctr[CTR_E2];
  float m = -INFINITY, ssum = 0.f, acc = 0.f;
  for (int e = 0; e <= ne; ++e){
    int s = (e < ne) ? E2src[e] : 0;
    int idx = (e < ne) ? (flag2[s] - 1) : 0;
    float xls = xl2[(size_t)idx * 64 + lane];
    float a = xls + xr;
    a = (a > 0.f) ? a : 0.2f * a;
    float lg = wave_sum(at * a);
    float mn = fmaxf(m, lg);
    float sc = expf(m - mn), p = expf(lg - mn);
    ssum = fmaf(ssum, sc, p);
    acc  = fmaf(acc,  sc, p * xls);
    m = mn;
  }
  float o = acc / (ssum + 1e-16f) + bias2[lane];
  float mu = wave_sum(o) * (1.f / 64.f);
  float dv = o - mu;
  float var = wave_sum(dv * dv) * (1.f / 64.f);
  float y = dv * rsqrtf(var + 1e-5f) * g2[lane] + be2[lane];
  float hv_v = (y > 0.f) ? y : expm1f(y);
  __shared__ float hv[64];
  hv[lane] = hv_v;
  __syncthreads();
  float contrib = 0.f;
  if (lane < 32){
    float a = rb1[lane];
    #pragma unroll 8
    for (int c = 0; c < 64; ++c) a = fmaf(hv[c], rw1[c * 32 + lane], a);
    float z = 0.5f * a * (1.f + erff(a * 0.70710678118654752f));
    contrib = z * rw2[lane];
  }
  float sfin = wave_sum(contrib);
  if (lane == 0) out[0] = sfin + rb2[0];
}

// ---------------- launch ----------------
extern "C" void kernel_launch(void* const* d_in, const int* in_sizes, int n_in,
                              void* d_out, int out_size, void* d_ws, size_t ws_size,
                              hipStream_t stream){
  const float* x    = (const float*)d_in[0];
  const int*   ei   = (const int*)  d_in[1];
  const float* Wl0  = (const float*)d_in[2];
  const float* bl0  = (const float*)d_in[3];
  const float* Wr0  = (const float*)d_in[4];
  const float* br0  = (const float*)d_in[5];
  const float* att0 = (const float*)d_in[6];
  const float* bias0= (const float*)d_in[7];
  const float* Wl1  = (const float*)d_in[8];
  const float* bl1  = (const float*)d_in[9];
  const float* Wr1  = (const float*)d_in[10];
  const float* br1  = (const float*)d_in[11];
  const float* att1 = (const float*)d_in[12];
  const float* bias1= (const float*)d_in[13];
  const float* Wl2  = (const float*)d_in[14];
  const float* bl2  = (const float*)d_in[15];
  const float* Wr2  = (const float*)d_in[16];
  const float* br2  = (const float*)d_in[17];
  const float* att2 = (const float*)d_in[18];
  const float* bias2= (const float*)d_in[19];
  const float* g2   = (const float*)d_in[24];
  const float* be2  = (const float*)d_in[25];
  const float* g0   = (const float*)d_in[20];
  const float* be0  = (const float*)d_in[21];
  const float* g1   = (const float*)d_in[22];
  const float* be1  = (const float*)d_in[23];
  const float* rw1  = (const float*)d_in[26];
  const float* rb1  = (const float*)d_in[27];
  const float* rw2  = (const float*)d_in[28];
  const float* rb2  = (const float*)d_in[29];

  const int N = in_sizes[0];        // 50000
  const int E = in_sizes[1] / 2;    // 800000

  char* ws = (char*)d_ws;
  size_t off = 0;
  auto alloc = [&](size_t bytes) -> char* {
    char* p = ws + off;
    off += (bytes + 255) & ~(size_t)255;
    return p;
  };
  int*   ctr     = (int*)  alloc(64);
  int*   flag1   = (int*)  alloc((size_t)N * 4);
  int*   flag2   = (int*)  alloc((size_t)N * 4);
  int*   list1   = (int*)  alloc((size_t)N * 4);
  int*   list2   = (int*)  alloc((size_t)N * 4);
  int*   counts0 = (int*)  alloc((size_t)N * 4);   // becomes cursor0 after scan
  int*   rowptr0 = (int*)  alloc((size_t)(N + 1) * 4);
  int*   srcs0   = (int*)  alloc((size_t)E * 4);
  int*   counts1 = (int*)  alloc((size_t)N * 4);   // becomes cursor1 after scan
  int*   rowptr1 = (int*)  alloc((size_t)(N + 1) * 4);
  int*   srcs1   = (int*)  alloc((size_t)E * 4);
  int*   E2src   = (int*)  alloc((size_t)E * 4);
  float* xr2     = (float*)alloc(64 * 4);
  float* xl2     = (float*)alloc((size_t)N * 64 * 4);
  float* h0      = (float*)alloc((size_t)N * 256 * 4);
  float* xl1     = (float*)alloc((size_t)N * 256 * 4);
  float* h1      = (float*)alloc((size_t)N * 256 * 4);
  (void)ws_size; (void)n_in; (void)out_size;

  int nb = (N + 255) / 256;
  int eb = (E + 255) / 256;

  // cone discovery
  k_init  <<<nb, 256, 0, stream>>>(flag1, flag2, counts0, counts1, list2, ctr, N);
  k_passA <<<eb, 256, 0, stream>>>(ei, E, flag2, list2, E2src, ctr);
  k_seed1 <<<1, 256, 0, stream>>>(list2, list1, flag1, ctr);
  k_passB1<<<eb, 256, 0, stream>>>(ei, E, flag2, counts1, flag1, list1, ctr);
  k_scan  <<<1, 1024, 0, stream>>>(counts1, rowptr1, ctr, CTR_CNT2);
  k_passB2<<<eb, 256, 0, stream>>>(ei, E, flag2, counts1, srcs1);
  k_passC1<<<eb, 256, 0, stream>>>(ei, E, flag1, counts0);
  k_scan  <<<1, 1024, 0, stream>>>(counts0, rowptr0, ctr, CTR_CNT1);
  k_passC2<<<eb, 256, 0, stream>>>(ei, E, flag1, counts0, srcs0);

  // layer 0 (xl0/xr0 on the fly from scalar x)
  k_l0agg <<<1024, 256, 0, stream>>>(x, Wl0, bl0, Wr0, br0, att0, bias0, g0, be0,
                                     list1, rowptr0, srcs0, ctr, h0);
  // layer 1
  k_l1proj<<<1024, 256, 0, stream>>>(h0, Wl1, bl1, list1, ctr, xl1);
  k_l1agg <<<256, 256, 0, stream>>>(h0, xl1, Wr1, br1, att1, bias1, g1, be1,
                                    list2, rowptr1, srcs1, ctr, h1);
  // layer 2 + head
  k_l2proj<<<256, 64, 0, stream>>>(h1, Wl2, bl2, Wr2, br2, list2, ctr, xl2, xr2);
  k_final <<<1, 64, 0, stream>>>(xl2, xr2, att2, bias2, g2, be2,
                                 rw1, rb1, rw2, rb2, E2src, flag2, ctr, (float*)d_out);
}